// Round 11
// baseline (317.600 us; speedup 1.0000x reference)
//
#include <hip/hip_runtime.h>
#include <hip/hip_cooperative_groups.h>

namespace cg = cooperative_groups;

#define N_NODES 50000
#define N_EDGES 800000
#define D 128
#define HP 256              // histogram / fill partition blocks (= grid of k_pre)
#define EPB (N_EDGES / HP)  // 3125 edges per partition
#define NW (N_NODES / 2)    // 25000 packed u32 words (2 nodes/word)
#define RNB 196             // ceil(N_NODES/256) reduce/scan node-blocks (256 nodes each)
#define NBLK 391            // ceil(N_NODES/128) fused gather+gemm blocks
#define DUMMY 50000         // zero-row index for CSR padding

typedef __attribute__((ext_vector_type(8))) short short8;   // 8 bf16
typedef __attribute__((ext_vector_type(4))) float f32x4;

__device__ __forceinline__ unsigned short f2bf(float f) {
    unsigned u = __float_as_uint(f);
    return (unsigned short)((u + 0x7FFFu + ((u >> 16) & 1u)) >> 16);  // RNE
}

// accumulate 16 bf16 (packed in two uint4) into 16 f32
__device__ __forceinline__ void acc16(float* a, uint4 v0, uint4 v1) {
    unsigned w0 = v0.x, w1 = v0.y, w2 = v0.z, w3 = v0.w;
    unsigned w4 = v1.x, w5 = v1.y, w6 = v1.z, w7 = v1.w;
    a[0]  += __uint_as_float(w0 << 16);  a[1]  += __uint_as_float(w0 & 0xFFFF0000u);
    a[2]  += __uint_as_float(w1 << 16);  a[3]  += __uint_as_float(w1 & 0xFFFF0000u);
    a[4]  += __uint_as_float(w2 << 16);  a[5]  += __uint_as_float(w2 & 0xFFFF0000u);
    a[6]  += __uint_as_float(w3 << 16);  a[7]  += __uint_as_float(w3 & 0xFFFF0000u);
    a[8]  += __uint_as_float(w4 << 16);  a[9]  += __uint_as_float(w4 & 0xFFFF0000u);
    a[10] += __uint_as_float(w5 << 16);  a[11] += __uint_as_float(w5 & 0xFFFF0000u);
    a[12] += __uint_as_float(w6 << 16);  a[13] += __uint_as_float(w6 & 0xFFFF0000u);
    a[14] += __uint_as_float(w7 << 16);  a[15] += __uint_as_float(w7 & 0xFFFF0000u);
}

// ==== ONE cooperative kernel for the whole prepipe: hist -> reduce+prescale ->
// scans -> fill, separated by grid.sync(). Rationale: R6/R7/R9 totals were
// pinned at 185-188us while per-kernel inner loops changed — the cost is the
// 6-dispatch serial pipeline (launch gaps + full-device drain per boundary),
// not any single loop. 256 blocks x 1024 thr, 112KB LDS -> exactly 1 block/CU
// co-resident (cooperative requirement). __launch_bounds__(1024) caps VGPR=128.
__global__ __launch_bounds__(1024) void k_pre(
        const int2* __restrict__ el2, unsigned int* __restrict__ partials,
        unsigned char* __restrict__ brel, int* __restrict__ deg_out,
        int* __restrict__ blk_sum, int* __restrict__ dhistT,
        int* __restrict__ blk_off, int* __restrict__ dcur,
        const float4* __restrict__ x4, uint4* __restrict__ xst,
        const float4* __restrict__ W4, ushort4* __restrict__ Wb4,
        int* __restrict__ row_start, int* __restrict__ order,
        unsigned short* __restrict__ srcs) {
    cg::grid_group grid = cg::this_grid();
    __shared__ unsigned int h[NW];   // 100 KB: hist counts, then fill cursors
    __shared__ int sc[256];
    __shared__ int hb[256];
    __shared__ int pre_i[4][256];
    __shared__ int pre_o[4][256];
    __shared__ float rsv[256];
    __shared__ int lcnt[256];
    const int t = threadIdx.x;
    const int b = blockIdx.x;

    // ---- phase 1: per-block LDS degree histogram over edge slice ----
    // LDS word w packs: in[2w](b0)|out[2w](b1)|in[2w+1](b2)|out[2w+1](b3), u8.
    for (int i = t; i < NW / 4; i += 1024) ((uint4*)h)[i] = make_uint4(0, 0, 0, 0);
    __syncthreads();
    {
        const int2* p = el2 + b * EPB;
        for (int i = t; i < EPB; i += 1024) {
            int2 st = p[i];
            atomicAdd(&h[st.x >> 1], 1u << ((st.x & 1) * 16));    // in-degree byte
            atomicAdd(&h[st.y >> 1], 256u << ((st.y & 1) * 16));  // out-degree byte
        }
    }
    __syncthreads();
    {
        uint4* dst = (uint4*)(partials + (size_t)b * NW);
        for (int i = t; i < NW / 4; i += 1024) dst[i] = ((uint4*)h)[i];
    }
    grid.sync();

    // ---- phase 2: reduce + fused prescale (196 active blocks, 4 thr/node,
    // v[64] in registers = 64-deep ILP on the partials read) ----
    if (b < RNB) {
        int nl = t & 255, ph = t >> 8;
        int pbase = ph * 64;
        int n = b * 256 + nl;
        bool ok = n < N_NODES;
        int w = n >> 1, shn = (n & 1) * 16;
        if (t < 256) hb[t] = 0;
        unsigned v[64];
        int si = 0, so = 0;
        if (ok) {
            #pragma unroll
            for (int j = 0; j < 64; ++j) v[j] = partials[(size_t)(pbase + j) * NW + w];
            #pragma unroll
            for (int j = 0; j < 64; ++j) {
                si += (int)((v[j] >> shn) & 0xFFu);
                so += (int)((v[j] >> (shn + 8)) & 0xFFu);
            }
        }
        pre_i[ph][nl] = si;
        pre_o[ph][nl] = so;
        __syncthreads();
        if (ok) {  // brel[p][n] = # out-edges of n in partitions < p (u8)
            int run = 0;
            #pragma unroll
            for (int q = 0; q < 4; ++q) if (q < ph) run += pre_o[q][nl];
            #pragma unroll
            for (int j = 0; j < 64; ++j) {
                brel[(size_t)(pbase + j) * N_NODES + n] = (unsigned char)run;
                run += (int)((v[j] >> (shn + 8)) & 0xFFu);
            }
        }
        if (ph == 0) {
            int si_t = pre_i[0][nl] + pre_i[1][nl] + pre_i[2][nl] + pre_i[3][nl];
            int so_t = pre_o[0][nl] + pre_o[1][nl] + pre_o[2][nl] + pre_o[3][nl];
            if (ok) {
                deg_out[n] = so_t;
                atomicAdd(&hb[so_t < 255 ? so_t : 255], 1);  // LDS atomics only
            }
            rsv[nl] = rsqrtf((float)(si_t + 1));
            sc[nl] = ok ? ((so_t + 3) & ~3) : 0;  // padded row size (mult of 4)
        }
        __syncthreads();  // rsv, sc visible; hb atomics done
        {   // fused prescale: xst[n][:] = bf16(rsqrt(deg_in+1)*x[n][:]), coalesced
            int nbase = b * 256;
            #pragma unroll
            for (int i = 0; i < 4; ++i) {
                int u = t + i * 1024;
                int node_l = u >> 4, part = u & 15;
                int node = nbase + node_l;
                if (node < N_NODES) {
                    float rs = rsv[node_l];
                    size_t g = (size_t)node * 16 + part;
                    float4 a = x4[g * 2], c = x4[g * 2 + 1];
                    uint4 o;
                    o.x = f2bf(rs * a.x) | ((unsigned)f2bf(rs * a.y) << 16);
                    o.y = f2bf(rs * a.z) | ((unsigned)f2bf(rs * a.w) << 16);
                    o.z = f2bf(rs * c.x) | ((unsigned)f2bf(rs * c.y) << 16);
                    o.w = f2bf(rs * c.z) | ((unsigned)f2bf(rs * c.w) << 16);
                    xst[g] = o;
                }
            }
        }
        __syncthreads();
        for (int s = 128; s > 0; s >>= 1) {
            if (t < s) sc[t] += sc[t + s];
            __syncthreads();
        }
        if (t == 0) blk_sum[b] = sc[0];
        if (t < 256) dhistT[t * RNB + b] = hb[t];   // transposed for the scan
    }
    grid.sync();

    // ---- phase 3: block 0 scans; block 1 converts W -> bf16 + zeroes DUMMY ----
    if (b == 1) {
        for (int i = t; i < 4096; i += 1024) {  // W: 16384 floats = 4096 float4
            float4 f = W4[i];
            ushort4 hh;
            hh.x = f2bf(f.x); hh.y = f2bf(f.y); hh.z = f2bf(f.z); hh.w = f2bf(f.w);
            Wb4[i] = hh;
        }
        if (t < 16) xst[(size_t)DUMMY * 16 + t] = make_uint4(0, 0, 0, 0);
    } else if (b == 0) {
        // all 1024 threads participate in barriers; work on t<256
        int v0 = (t < RNB) ? blk_sum[t] : 0;
        if (t < 256) sc[t] = v0;
        __syncthreads();
        for (int off = 1; off < 256; off <<= 1) {
            int a = (t >= off && t < 256) ? sc[t - off] : 0;
            __syncthreads();
            if (t < 256) sc[t] += a;
            __syncthreads();
        }
        if (t < RNB) blk_off[t] = sc[t] - v0;  // exclusive
        __syncthreads();
        int s = 0;
        if (t < 256) {
            for (int i = 0; i < RNB; ++i) s += dhistT[t * RNB + i];
            sc[255 - t] = s;  // descending-degree layout
        }
        __syncthreads();
        for (int off = 1; off < 256; off <<= 1) {
            int a = (t >= off && t < 256) ? sc[t - off] : 0;
            __syncthreads();
            if (t < 256) sc[t] += a;
            __syncthreads();
        }
        if (t < 256) {
            int run = sc[255 - t] - s;  // exclusive prefix for degree t
            for (int i = 0; i < RNB; ++i) {
                int c = dhistT[t * RNB + i];
                dcur[t * RNB + i] = run;
                run += c;
            }
        }
    }
    grid.sync();

    // ---- phase 4: row_start (padded x4) + degree-sort placement + pad fill ----
    if (b < RNB) {
        if (t < 256) lcnt[t] = 0;
        int n = b * 256 + t;
        int vdeg = (t < 256 && n < N_NODES) ? deg_out[n] : 0;
        int ps = (vdeg + 3) & ~3;
        if (t < 256) sc[t] = ps;
        __syncthreads();
        for (int off = 1; off < 256; off <<= 1) {
            int a = (t >= off && t < 256) ? sc[t - off] : 0;
            __syncthreads();
            if (t < 256) sc[t] += a;
            __syncthreads();
        }
        if (t < 256 && n < N_NODES) {
            int base = blk_off[b] + sc[t] - ps;
            row_start[n] = base;
            for (int j = vdeg; j < ps; ++j) srcs[base + j] = DUMMY;
            int dd = vdeg < 255 ? vdeg : 255;
            int r = atomicAdd(&lcnt[dd], 1);  // LDS atomics only
            order[dcur[dd * RNB + b] + r] = n;
        }
    }
    grid.sync();

    // ---- phase 5: counting-sort edge placement (h reused as u16 cursors) ----
    for (int i = t; i < NW / 4; i += 1024) ((uint4*)h)[i] = make_uint4(0, 0, 0, 0);
    __syncthreads();
    {
        const int2* p = el2 + b * EPB;
        const unsigned char* br = brel + (size_t)b * N_NODES;
        for (int i = t; i < EPB; i += 1024) {
            int2 st = p[i];
            int n = st.y;
            unsigned old = atomicAdd(&h[n >> 1], 1u << ((n & 1) * 16));
            int rank = (old >> ((n & 1) * 16)) & 0xFFFF;
            srcs[row_start[n] + (int)br[n] + rank] = (unsigned short)st.x;
        }
    }
}

// ---- fused gather + GEMM: per block 128 degree-sorted nodes, 1024 threads.
// R9's best-measured form (45us): single-pass gather, 8 lanes/node, full 256B
// row per edge, index prefetch. R10's reg double-buffer REGRESSED (VGPR=64 ->
// compiler spilled: WRITE 25->47MB, 51us) — keep the simple loop. W staged in
// LDS; snake + degree sort balance per-CU work. 2 blocks/CU = 32 waves.
// min-waves=4 keeps VGPR cap 128 (R3: =8 clamped+spilled).
__global__ __launch_bounds__(1024, 4) void k_gg(const unsigned short* __restrict__ Wb,
                                                const float* __restrict__ bias,
                                                const unsigned short* __restrict__ xst,
                                                const unsigned short* __restrict__ srcs,
                                                const int* __restrict__ row_start,
                                                const int* __restrict__ deg_out,
                                                const int* __restrict__ order,
                                                float* __restrict__ out) {
    __shared__ unsigned short Wl[128 * 136];  // 34.8 KB
    __shared__ unsigned short As[128 * 136];  // 34.8 KB
    const int tid = threadIdx.x;

    // stage Wb (bf16, 32 KB) -> LDS once per block
    for (int i = tid; i < 2048; i += 1024) {
        int r = i >> 4, c = i & 15;
        *(uint4*)&Wl[r * 136 + c * 8] = ((const uint4*)Wb)[i];
    }

    // snake mapping: rounds of 256, odd rounds reversed
    int b = blockIdx.x;
    int rr = b >> 8, pos = b & 255;
    int rbase = rr << 8;
    int cntr = NBLK - rbase; if (cntr > 256) cntr = 256;
    int tile = (rr & 1) ? (rbase + cntr - 1 - pos) : b;

    // ---- phase 1: gather ----
    const int slot = tid >> 3;            // As row 0..127
    const int d = tid & 7;                // 16-feature slice
    const int gslot = tile * 128 + slot;
    float acc[16];
    #pragma unroll
    for (int i = 0; i < 16; ++i) acc[i] = 0.f;

    if (gslot < N_NODES) {
        const int node = order[gslot];
        const int cnt = deg_out[node];
        const int cntp = (cnt + 3) & ~3;  // padded (pads -> DUMMY zero row)
        const uint4* xb = (const uint4*)xst;
        const int dof = d * 2;
        {   // self term (already rs-scaled)
            const uint4* xr = xb + (size_t)node * 16 + dof;
            acc16(acc, xr[0], xr[1]);
        }
        const unsigned short* p = srcs + row_start[node];  // 8B-aligned (rows %4)
        ushort4 s4 = *(const ushort4*)&p[0];
        for (int k = 0; k < cntp; k += 4) {
            ushort4 nx = *(const ushort4*)&p[k + 4];  // prefetch next chunk
            const uint4* r0 = xb + (size_t)s4.x * 16 + dof;
            const uint4* r1 = xb + (size_t)s4.y * 16 + dof;
            const uint4* r2 = xb + (size_t)s4.z * 16 + dof;
            const uint4* r3 = xb + (size_t)s4.w * 16 + dof;
            uint4 a0 = r0[0], b0 = r0[1];
            uint4 a1 = r1[0], b1 = r1[1];
            uint4 a2 = r2[0], b2 = r2[1];
            uint4 a3 = r3[0], b3 = r3[1];
            acc16(acc, a0, b0); acc16(acc, a1, b1);
            acc16(acc, a2, b2); acc16(acc, a3, b3);
            s4 = nx;
        }
        float rd = rsqrtf((float)(cnt + 1));
        #pragma unroll
        for (int i = 0; i < 16; ++i) acc[i] *= rd;
    }
    {   // pack 16 f32 -> 16 bf16 -> LDS (invalid slots write zeros; no early return!)
        unsigned wpk[8];
        #pragma unroll
        for (int i = 0; i < 8; ++i)
            wpk[i] = (unsigned)f2bf(acc[2 * i]) | ((unsigned)f2bf(acc[2 * i + 1]) << 16);
        uint4* dst = (uint4*)&As[slot * 136 + d * 16];
        dst[0] = make_uint4(wpk[0], wpk[1], wpk[2], wpk[3]);
        dst[1] = make_uint4(wpk[4], wpk[5], wpk[6], wpk[7]);
    }
    __syncthreads();

    // ---- phase 2: 128x128 GEMM, 16 waves = 8 row-tiles x 2 col-halves ----
    const int wv = tid >> 6, lane = tid & 63, ml = lane & 15, q = lane >> 4;
    const int rt = wv & 7, half = wv >> 3;
    const int arow = rt * 16 + ml;
    short8 a[4];
    #pragma unroll
    for (int kt = 0; kt < 4; ++kt)
        a[kt] = *(const short8*)&As[arow * 136 + kt * 32 + q * 8];

    f32x4 accm[4];
    #pragma unroll
    for (int jj = 0; jj < 4; ++jj) accm[jj] = (f32x4){0.f, 0.f, 0.f, 0.f};
    #pragma unroll
    for (int jj = 0; jj < 4; ++jj) {
        #pragma unroll
        for (int kt = 0; kt < 4; ++kt) {
            short8 bw = *(const short8*)&Wl[(half * 64 + jj * 16 + ml) * 136 + kt * 32 + q * 8];
            accm[jj] = __builtin_amdgcn_mfma_f32_16x16x32_bf16(a[kt], bw, accm[jj], 0, 0, 0);
        }
    }
    #pragma unroll
    for (int jj = 0; jj < 4; ++jj) {
        float bj = bias[half * 64 + jj * 16 + ml];
        #pragma unroll
        for (int r4 = 0; r4 < 4; ++r4) {
            int s = rt * 16 + q * 4 + r4;
            int gs = tile * 128 + s;
            if (gs < N_NODES) {
                int nd = order[gs];
                float v = accm[jj][r4] + bj;
                out[nd * D + half * 64 + jj * 16 + ml] = v > 0.f ? v : 0.f;
            }
        }
    }
}

extern "C" void kernel_launch(void* const* d_in, const int* in_sizes, int n_in,
                              void* d_out, int out_size, void* d_ws, size_t ws_size,
                              hipStream_t stream) {
    const int*   el = (const int*)d_in[0];
    const float* x  = (const float*)d_in[1];
    const float* W  = (const float*)d_in[2];
    const float* b  = (const float*)d_in[3];
    float* out = (float*)d_out;

    // workspace layout (~54 MB)
    unsigned int* partials = (unsigned int*)d_ws;                            // HP*NW u32 = 25.6M
    unsigned short* xst    = (unsigned short*)(partials + (size_t)HP * NW);  // (N+1)*128 bf16
    unsigned char* brel    = (unsigned char*)(xst + (size_t)(N_NODES + 1) * D); // HP*N u8 = 12.8M
    unsigned short* srcs   = (unsigned short*)(brel + (size_t)HP * N_NODES); // <=1M u16 (pad x4)
    int* deg_out   = (int*)(srcs + 1000000);                                 // N
    int* row_start = deg_out + N_NODES;                                      // N
    int* blk_sum   = row_start + N_NODES;                                    // 256
    int* blk_off   = blk_sum + 256;                                          // 256
    int* dhistT    = blk_off + 256;                                          // 256*RNB = 50176
    int* dcur      = dhistT + 256 * RNB;                                     // 50176
    int* order     = dcur + 256 * RNB;                                       // N
    unsigned short* Wb = (unsigned short*)(order + N_NODES);                 // 128*128 bf16

    const int2* el2 = (const int2*)el;
    const float4* x4 = (const float4*)x;
    uint4* xst4 = (uint4*)xst;
    const float4* W4 = (const float4*)W;
    ushort4* Wb4 = (ushort4*)Wb;

    void* args[] = {
        (void*)&el2, (void*)&partials, (void*)&brel, (void*)&deg_out,
        (void*)&blk_sum, (void*)&dhistT, (void*)&blk_off, (void*)&dcur,
        (void*)&x4, (void*)&xst4, (void*)&W4, (void*)&Wb4,
        (void*)&row_start, (void*)&order, (void*)&srcs
    };
    hipLaunchCooperativeKernel((void*)k_pre, dim3(HP), dim3(1024), args, 0, stream);
    k_gg<<<NBLK, 1024, 0, stream>>>(Wb, b, xst, srcs, row_start, deg_out, order, out);
}

// Round 12
// 186.327 us; speedup vs baseline: 1.7045x; 1.7045x over previous
//
#include <hip/hip_runtime.h>

#define N_NODES 50000
#define N_EDGES 800000
#define D 128
#define HP 128              // histogram / fill partition blocks
#define EPB (N_EDGES / HP)  // 6250 edges per partition
#define NW (N_NODES / 2)    // 25000 packed u32 words (2 nodes/word)
#define RNB 196             // ceil(N_NODES/256) reduce/scan blocks (256 nodes each)
#define NBLK 391            // ceil(N_NODES/128) fused gather+gemm blocks
#define DUMMY 50000         // zero-row index for CSR padding

typedef __attribute__((ext_vector_type(8))) short short8;   // 8 bf16
typedef __attribute__((ext_vector_type(4))) float f32x4;

__device__ __forceinline__ unsigned short f2bf(float f) {
    unsigned u = __float_as_uint(f);
    return (unsigned short)((u + 0x7FFFu + ((u >> 16) & 1u)) >> 16);  // RNE
}

// accumulate 16 bf16 (packed in two uint4) into 16 f32
__device__ __forceinline__ void acc16(float* a, uint4 v0, uint4 v1) {
    unsigned w0 = v0.x, w1 = v0.y, w2 = v0.z, w3 = v0.w;
    unsigned w4 = v1.x, w5 = v1.y, w6 = v1.z, w7 = v1.w;
    a[0]  += __uint_as_float(w0 << 16);  a[1]  += __uint_as_float(w0 & 0xFFFF0000u);
    a[2]  += __uint_as_float(w1 << 16);  a[3]  += __uint_as_float(w1 & 0xFFFF0000u);
    a[4]  += __uint_as_float(w2 << 16);  a[5]  += __uint_as_float(w2 & 0xFFFF0000u);
    a[6]  += __uint_as_float(w3 << 16);  a[7]  += __uint_as_float(w3 & 0xFFFF0000u);
    a[8]  += __uint_as_float(w4 << 16);  a[9]  += __uint_as_float(w4 & 0xFFFF0000u);
    a[10] += __uint_as_float(w5 << 16);  a[11] += __uint_as_float(w5 & 0xFFFF0000u);
    a[12] += __uint_as_float(w6 << 16);  a[13] += __uint_as_float(w6 & 0xFFFF0000u);
    a[14] += __uint_as_float(w7 << 16);  a[15] += __uint_as_float(w7 & 0xFFFF0000u);
}

// ---- degrees via per-block LDS histograms, 1024 threads (16 waves/block).
// LDS word w packs: in[2w](b0)|out[2w](b1)|in[2w+1](b2)|out[2w+1](b3), u8 each.
__global__ __launch_bounds__(1024) void k_hist(const int2* __restrict__ el2,
                                               unsigned int* __restrict__ partials) {
    __shared__ unsigned int h[NW];  // 100 KB
    int t = threadIdx.x;
    for (int i = t; i < NW / 4; i += 1024) ((uint4*)h)[i] = make_uint4(0, 0, 0, 0);
    __syncthreads();
    const int2* p = el2 + blockIdx.x * EPB;
    for (int i = t; i < EPB; i += 1024) {
        int2 st = p[i];
        atomicAdd(&h[st.x >> 1], 1u << ((st.x & 1) * 16));       // in-degree byte
        atomicAdd(&h[st.y >> 1], 256u << ((st.y & 1) * 16));     // out-degree byte
    }
    __syncthreads();
    uint4* dst = (uint4*)(partials + (size_t)blockIdx.x * NW);
    for (int i = t; i < NW / 4; i += 1024) dst[i] = ((uint4*)h)[i];
}

// ---- reduce, 1024 threads = 4 threads/node, phase = 32 partitions, v[32] in
// registers. SPILL FIX (R11 diagnosis): the v[64] version compiled to VGPR=52
// -> the whole batch lived in scratch (~50MB round-trip, 0.7TB/s) — the 64-deep
// ILP never existed. v[32] (~60 VGPR) + explicit (1024,4) cap=128 keeps the
// batch in registers. Cross-phase prefix via LDS. Fused prescale: xst[n][:] =
// bf16(rsqrt(deg_in+1)*x[n][:]). Also: padded block sums + dhistT (transposed).
__global__ __launch_bounds__(1024, 4) void k_reduce(const unsigned int* __restrict__ partials,
                                                    unsigned char* __restrict__ brel,
                                                    int* __restrict__ deg_out,
                                                    int* __restrict__ blk_sum,
                                                    int* __restrict__ dhistT,
                                                    const float4* __restrict__ x4,
                                                    uint4* __restrict__ xst) {
    __shared__ int sc[256];
    __shared__ int hb[256];
    __shared__ int pre_i[4][256];
    __shared__ int pre_o[4][256];
    __shared__ float rsv[256];
    int t = threadIdx.x;
    int nl = t & 255, ph = t >> 8;
    int pbase = ph * 32;
    int n = blockIdx.x * 256 + nl;
    bool ok = n < N_NODES;
    int w = n >> 1, sh = (n & 1) * 16;
    if (t < 256) hb[t] = 0;
    unsigned v[32];
    int si = 0, so = 0;
    if (ok) {
        #pragma unroll
        for (int j = 0; j < 32; ++j) v[j] = partials[(size_t)(pbase + j) * NW + w];
        #pragma unroll
        for (int j = 0; j < 32; ++j) {
            si += (int)((v[j] >> sh) & 0xFFu);
            so += (int)((v[j] >> (sh + 8)) & 0xFFu);
        }
    }
    pre_i[ph][nl] = si;
    pre_o[ph][nl] = so;
    __syncthreads();
    if (ok) {  // brel[p][n] = # out-edges of n in partitions < p (u8)
        int run = 0;
        #pragma unroll
        for (int q = 0; q < 4; ++q) if (q < ph) run += pre_o[q][nl];
        #pragma unroll
        for (int j = 0; j < 32; ++j) {
            brel[(size_t)(pbase + j) * N_NODES + n] = (unsigned char)run;
            run += (int)((v[j] >> (sh + 8)) & 0xFFu);
        }
    }
    if (ph == 0) {
        int si_t = pre_i[0][nl] + pre_i[1][nl] + pre_i[2][nl] + pre_i[3][nl];
        int so_t = pre_o[0][nl] + pre_o[1][nl] + pre_o[2][nl] + pre_o[3][nl];
        if (ok) {
            deg_out[n] = so_t;
            atomicAdd(&hb[so_t < 255 ? so_t : 255], 1);  // LDS atomics only
        }
        rsv[nl] = rsqrtf((float)(si_t + 1));
        sc[nl] = ok ? ((so_t + 3) & ~3) : 0;  // padded row size (mult of 4)
    }
    __syncthreads();  // rsv, sc visible; hb atomics done
    // fused prescale: 256 nodes x 16 parts = 4096 tasks, 4 per thread, coalesced
    {
        int nbase = blockIdx.x * 256;
        #pragma unroll
        for (int i = 0; i < 4; ++i) {
            int u = t + i * 1024;
            int node_l = u >> 4, part = u & 15;
            int node = nbase + node_l;
            if (node < N_NODES) {
                float rs = rsv[node_l];
                size_t g = (size_t)node * 16 + part;
                float4 a = x4[g * 2], c = x4[g * 2 + 1];
                uint4 o;
                o.x = f2bf(rs * a.x) | ((unsigned)f2bf(rs * a.y) << 16);
                o.y = f2bf(rs * a.z) | ((unsigned)f2bf(rs * a.w) << 16);
                o.z = f2bf(rs * c.x) | ((unsigned)f2bf(rs * c.y) << 16);
                o.w = f2bf(rs * c.z) | ((unsigned)f2bf(rs * c.w) << 16);
                xst[g] = o;
            }
        }
    }
    __syncthreads();
    for (int s = 128; s > 0; s >>= 1) {
        if (t < s) sc[t] += sc[t + s];
        __syncthreads();
    }
    if (t == 0) blk_sum[blockIdx.x] = sc[0];
    if (t < 256) dhistT[t * RNB + blockIdx.x] = hb[t];   // transposed for k_scan_b
}

// block 0: exclusive scan of RNB (padded) block sums + (deg DESC, blk) bins ->
// absolute base offsets dcur[deg][blk]. block 1: W -> bf16 + zero DUMMY row.
__global__ void k_scan_b(const int* __restrict__ blk_sum, int* __restrict__ blk_off,
                         const int* __restrict__ dhistT, int* __restrict__ dcur,
                         const float4* __restrict__ W4, ushort4* __restrict__ Wb4,
                         uint4* __restrict__ xst) {
    int t = threadIdx.x;
    if (blockIdx.x == 1) {
        for (int i = t; i < 4096; i += 256) {  // W: 16384 floats = 4096 float4
            float4 f = W4[i];
            ushort4 h;
            h.x = f2bf(f.x); h.y = f2bf(f.y); h.z = f2bf(f.z); h.w = f2bf(f.w);
            Wb4[i] = h;
        }
        if (t < 16) xst[(size_t)DUMMY * 16 + t] = make_uint4(0, 0, 0, 0);
        return;
    }
    __shared__ int sc[256];
    int v = (t < RNB) ? blk_sum[t] : 0;
    sc[t] = v;
    __syncthreads();
    for (int off = 1; off < 256; off <<= 1) {
        int a = (t >= off) ? sc[t - off] : 0;
        __syncthreads();
        sc[t] += a;
        __syncthreads();
    }
    if (t < RNB) blk_off[t] = sc[t] - v;  // exclusive
    __syncthreads();
    // thread t owns degree d=t; rows of dhistT are contiguous (RNB ints)
    int s = 0;
    #pragma unroll
    for (int i = 0; i < RNB; ++i) s += dhistT[t * RNB + i];
    sc[255 - t] = s;  // descending-degree order: slot u = 255-d
    __syncthreads();
    for (int off = 1; off < 256; off <<= 1) {
        int a = (t >= off) ? sc[t - off] : 0;
        __syncthreads();
        sc[t] += a;
        __syncthreads();
    }
    int run = sc[255 - t] - s;  // exclusive prefix for degree t (descending layout)
    #pragma unroll
    for (int i = 0; i < RNB; ++i) {
        int c = dhistT[t * RNB + i];
        dcur[t * RNB + i] = run;
        run += c;
    }
}

// row_start (PADDED x4) thread-per-node + deterministic degree-sort placement
// + CSR pad-slot fill (DUMMY -> zero row). order[] is DESCENDING degree.
__global__ void k_scan_c(const int* __restrict__ deg_out, const int* __restrict__ blk_off,
                         int* __restrict__ row_start, const int* __restrict__ dcur,
                         int* __restrict__ order, unsigned short* __restrict__ srcs) {
    __shared__ int sc[256];
    __shared__ int lcnt[256];
    int t = threadIdx.x;
    lcnt[t] = 0;
    int n = blockIdx.x * 256 + t;
    int v = (n < N_NODES) ? deg_out[n] : 0;
    int ps = (v + 3) & ~3;
    sc[t] = ps;
    __syncthreads();  // also makes lcnt zeroing visible
    for (int off = 1; off < 256; off <<= 1) {
        int a = (t >= off) ? sc[t - off] : 0;
        __syncthreads();
        sc[t] += a;
        __syncthreads();
    }
    if (n < N_NODES) {
        int base = blk_off[blockIdx.x] + sc[t] - ps;
        row_start[n] = base;
        for (int j = v; j < ps; ++j) srcs[base + j] = DUMMY;
        int d = v < 255 ? v : 255;
        int r = atomicAdd(&lcnt[d], 1);  // LDS atomics only
        order[dcur[d * RNB + blockIdx.x] + r] = n;
    }
}

// ---- counting-sort placement, 1024 threads, NO global atomics ----
__global__ __launch_bounds__(1024) void k_fill(const int2* __restrict__ el2,
                                               const int* __restrict__ row_start,
                                               const unsigned char* __restrict__ brel,
                                               unsigned short* __restrict__ srcs) {
    __shared__ unsigned int cur[NW];  // 100 KB packed u16 cursors
    int t = threadIdx.x;
    for (int i = t; i < NW / 4; i += 1024) ((uint4*)cur)[i] = make_uint4(0, 0, 0, 0);
    __syncthreads();
    const int2* p = el2 + blockIdx.x * EPB;
    const unsigned char* br = brel + (size_t)blockIdx.x * N_NODES;
    for (int i = t; i < EPB; i += 1024) {
        int2 st = p[i];
        int n = st.y;
        unsigned old = atomicAdd(&cur[n >> 1], 1u << ((n & 1) * 16));
        int rank = (old >> ((n & 1) * 16)) & 0xFFFF;
        srcs[row_start[n] + (int)br[n] + rank] = (unsigned short)st.x;
    }
}

// ---- fused gather + GEMM: per block 128 degree-sorted nodes, 1024 threads.
// R9's best-measured form (45us): single-pass gather, 8 lanes/node, full 256B
// row per edge, index prefetch. (R10 reg double-buffer spilled; R8 feature
// striping overfetched 128B lines — both reverted.) W staged in LDS; snake +
// degree sort balance per-CU work. 2 blocks/CU = 32 waves.
// min-waves=4 keeps VGPR cap 128 (R3: =8 clamped+spilled).
__global__ __launch_bounds__(1024, 4) void k_gg(const unsigned short* __restrict__ Wb,
                                                const float* __restrict__ bias,
                                                const unsigned short* __restrict__ xst,
                                                const unsigned short* __restrict__ srcs,
                                                const int* __restrict__ row_start,
                                                const int* __restrict__ deg_out,
                                                const int* __restrict__ order,
                                                float* __restrict__ out) {
    __shared__ unsigned short Wl[128 * 136];  // 34.8 KB
    __shared__ unsigned short As[128 * 136];  // 34.8 KB
    const int tid = threadIdx.x;

    // stage Wb (bf16, 32 KB) -> LDS once per block
    for (int i = tid; i < 2048; i += 1024) {
        int r = i >> 4, c = i & 15;
        *(uint4*)&Wl[r * 136 + c * 8] = ((const uint4*)Wb)[i];
    }

    // snake mapping: rounds of 256, odd rounds reversed
    int b = blockIdx.x;
    int rr = b >> 8, pos = b & 255;
    int rbase = rr << 8;
    int cntr = NBLK - rbase; if (cntr > 256) cntr = 256;
    int tile = (rr & 1) ? (rbase + cntr - 1 - pos) : b;

    // ---- phase 1: gather ----
    const int slot = tid >> 3;            // As row 0..127
    const int d = tid & 7;                // 16-feature slice
    const int gslot = tile * 128 + slot;
    float acc[16];
    #pragma unroll
    for (int i = 0; i < 16; ++i) acc[i] = 0.f;

    if (gslot < N_NODES) {
        const int node = order[gslot];
        const int cnt = deg_out[node];
        const int cntp = (cnt + 3) & ~3;  // padded (pads -> DUMMY zero row)
        const uint4* xb = (const uint4*)xst;
        const int dof = d * 2;
        {   // self term (already rs-scaled)
            const uint4* xr = xb + (size_t)node * 16 + dof;
            acc16(acc, xr[0], xr[1]);
        }
        const unsigned short* p = srcs + row_start[node];  // 8B-aligned (rows %4)
        ushort4 s4 = *(const ushort4*)&p[0];
        for (int k = 0; k < cntp; k += 4) {
            ushort4 nx = *(const ushort4*)&p[k + 4];  // prefetch next chunk
            const uint4* r0 = xb + (size_t)s4.x * 16 + dof;
            const uint4* r1 = xb + (size_t)s4.y * 16 + dof;
            const uint4* r2 = xb + (size_t)s4.z * 16 + dof;
            const uint4* r3 = xb + (size_t)s4.w * 16 + dof;
            uint4 a0 = r0[0], b0 = r0[1];
            uint4 a1 = r1[0], b1 = r1[1];
            uint4 a2 = r2[0], b2 = r2[1];
            uint4 a3 = r3[0], b3 = r3[1];
            acc16(acc, a0, b0); acc16(acc, a1, b1);
            acc16(acc, a2, b2); acc16(acc, a3, b3);
            s4 = nx;
        }
        float rd = rsqrtf((float)(cnt + 1));
        #pragma unroll
        for (int i = 0; i < 16; ++i) acc[i] *= rd;
    }
    {   // pack 16 f32 -> 16 bf16 -> LDS (invalid slots write zeros; no early return!)
        unsigned wpk[8];
        #pragma unroll
        for (int i = 0; i < 8; ++i)
            wpk[i] = (unsigned)f2bf(acc[2 * i]) | ((unsigned)f2bf(acc[2 * i + 1]) << 16);
        uint4* dst = (uint4*)&As[slot * 136 + d * 16];
        dst[0] = make_uint4(wpk[0], wpk[1], wpk[2], wpk[3]);
        dst[1] = make_uint4(wpk[4], wpk[5], wpk[6], wpk[7]);
    }
    __syncthreads();

    // ---- phase 2: 128x128 GEMM, 16 waves = 8 row-tiles x 2 col-halves ----
    const int wv = tid >> 6, lane = tid & 63, ml = lane & 15, q = lane >> 4;
    const int rt = wv & 7, half = wv >> 3;
    const int arow = rt * 16 + ml;
    short8 a[4];
    #pragma unroll
    for (int kt = 0; kt < 4; ++kt)
        a[kt] = *(const short8*)&As[arow * 136 + kt * 32 + q * 8];

    f32x4 accm[4];
    #pragma unroll
    for (int jj = 0; jj < 4; ++jj) accm[jj] = (f32x4){0.f, 0.f, 0.f, 0.f};
    #pragma unroll
    for (int jj = 0; jj < 4; ++jj) {
        #pragma unroll
        for (int kt = 0; kt < 4; ++kt) {
            short8 bw = *(const short8*)&Wl[(half * 64 + jj * 16 + ml) * 136 + kt * 32 + q * 8];
            accm[jj] = __builtin_amdgcn_mfma_f32_16x16x32_bf16(a[kt], bw, accm[jj], 0, 0, 0);
        }
    }
    #pragma unroll
    for (int jj = 0; jj < 4; ++jj) {
        float bj = bias[half * 64 + jj * 16 + ml];
        #pragma unroll
        for (int r4 = 0; r4 < 4; ++r4) {
            int s = rt * 16 + q * 4 + r4;
            int gs = tile * 128 + s;
            if (gs < N_NODES) {
                int nd = order[gs];
                float v = accm[jj][r4] + bj;
                out[nd * D + half * 64 + jj * 16 + ml] = v > 0.f ? v : 0.f;
            }
        }
    }
}

extern "C" void kernel_launch(void* const* d_in, const int* in_sizes, int n_in,
                              void* d_out, int out_size, void* d_ws, size_t ws_size,
                              hipStream_t stream) {
    const int*   el = (const int*)d_in[0];
    const float* x  = (const float*)d_in[1];
    const float* W  = (const float*)d_in[2];
    const float* b  = (const float*)d_in[3];
    float* out = (float*)d_out;

    // workspace layout (~35 MB)
    unsigned int* partials = (unsigned int*)d_ws;                            // HP*NW u32 = 12.8M
    unsigned short* xst    = (unsigned short*)(partials + (size_t)HP * NW);  // (N+1)*128 bf16
    unsigned char* brel    = (unsigned char*)(xst + (size_t)(N_NODES + 1) * D); // HP*N u8 = 6.4M
    unsigned short* srcs   = (unsigned short*)(brel + (size_t)HP * N_NODES); // <=1M u16 (pad x4)
    int* deg_out   = (int*)(srcs + 1000000);                                 // N
    int* row_start = deg_out + N_NODES;                                      // N
    int* blk_sum   = row_start + N_NODES;                                    // 256
    int* blk_off   = blk_sum + 256;                                          // 256
    int* dhistT    = blk_off + 256;                                          // 256*RNB = 50176
    int* dcur      = dhistT + 256 * RNB;                                     // 50176
    int* order     = dcur + 256 * RNB;                                       // N
    unsigned short* Wb = (unsigned short*)(order + N_NODES);                 // 128*128 bf16

    k_hist<<<HP, 1024, 0, stream>>>((const int2*)el, partials);
    k_reduce<<<RNB, 1024, 0, stream>>>(partials, brel, deg_out, blk_sum, dhistT,
                                       (const float4*)x, (uint4*)xst);
    k_scan_b<<<2, 256, 0, stream>>>(blk_sum, blk_off, dhistT, dcur,
                                    (const float4*)W, (ushort4*)Wb, (uint4*)xst);
    k_scan_c<<<RNB, 256, 0, stream>>>(deg_out, blk_off, row_start, dcur, order, srcs);
    k_fill<<<HP, 1024, 0, stream>>>((const int2*)el, row_start, brel, srcs);
    k_gg<<<NBLK, 1024, 0, stream>>>(Wb, b, xst, srcs, row_start, deg_out, order, out);
}

// Round 13
// 183.592 us; speedup vs baseline: 1.7299x; 1.0149x over previous
//
#include <hip/hip_runtime.h>

#define N_NODES 50000
#define N_EDGES 800000
#define D 128
#define HP 128              // histogram / fill partition blocks
#define EPB (N_EDGES / HP)  // 6250 edges per partition
#define NW (N_NODES / 2)    // 25000 packed u32 words (2 nodes/word)
#define RNB 196             // ceil(N_NODES/256) reduce/scan blocks (256 nodes each)
#define NBLK 391            // ceil(N_NODES/128) fused gather+gemm blocks
#define DUMMY 50000         // zero-row index for CSR padding

typedef __attribute__((ext_vector_type(8))) short short8;   // 8 bf16
typedef __attribute__((ext_vector_type(4))) float f32x4;

__device__ __forceinline__ unsigned short f2bf(float f) {
    unsigned u = __float_as_uint(f);
    return (unsigned short)((u + 0x7FFFu + ((u >> 16) & 1u)) >> 16);  // RNE
}

// accumulate 16 bf16 (packed in two uint4) into 16 f32
__device__ __forceinline__ void acc16(float* a, uint4 v0, uint4 v1) {
    unsigned w0 = v0.x, w1 = v0.y, w2 = v0.z, w3 = v0.w;
    unsigned w4 = v1.x, w5 = v1.y, w6 = v1.z, w7 = v1.w;
    a[0]  += __uint_as_float(w0 << 16);  a[1]  += __uint_as_float(w0 & 0xFFFF0000u);
    a[2]  += __uint_as_float(w1 << 16);  a[3]  += __uint_as_float(w1 & 0xFFFF0000u);
    a[4]  += __uint_as_float(w2 << 16);  a[5]  += __uint_as_float(w2 & 0xFFFF0000u);
    a[6]  += __uint_as_float(w3 << 16);  a[7]  += __uint_as_float(w3 & 0xFFFF0000u);
    a[8]  += __uint_as_float(w4 << 16);  a[9]  += __uint_as_float(w4 & 0xFFFF0000u);
    a[10] += __uint_as_float(w5 << 16);  a[11] += __uint_as_float(w5 & 0xFFFF0000u);
    a[12] += __uint_as_float(w6 << 16);  a[13] += __uint_as_float(w6 & 0xFFFF0000u);
    a[14] += __uint_as_float(w7 << 16);  a[15] += __uint_as_float(w7 & 0xFFFF0000u);
}

// ---- degrees via per-block LDS histograms, 1024 threads (16 waves/block).
// LDS word w packs: in[2w](b0)|out[2w](b1)|in[2w+1](b2)|out[2w+1](b3), u8 each.
__global__ __launch_bounds__(1024) void k_hist(const int2* __restrict__ el2,
                                               unsigned int* __restrict__ partials) {
    __shared__ unsigned int h[NW];  // 100 KB
    int t = threadIdx.x;
    for (int i = t; i < NW / 4; i += 1024) ((uint4*)h)[i] = make_uint4(0, 0, 0, 0);
    __syncthreads();
    const int2* p = el2 + blockIdx.x * EPB;
    for (int i = t; i < EPB; i += 1024) {
        int2 st = p[i];
        atomicAdd(&h[st.x >> 1], 1u << ((st.x & 1) * 16));       // in-degree byte
        atomicAdd(&h[st.y >> 1], 256u << ((st.y & 1) * 16));     // out-degree byte
    }
    __syncthreads();
    uint4* dst = (uint4*)(partials + (size_t)blockIdx.x * NW);
    for (int i = t; i < NW / 4; i += 1024) dst[i] = ((uint4*)h)[i];
}

// ---- reduce, 1024 threads = 4 threads/node, phase = 32 partitions, v[32] in
// registers (spill-safe: ~60 VGPR, (1024,4) cap=128). Cross-phase prefix via
// LDS. Fused prescale: xst[n][:] = bf16(rsqrt(deg_in+1)*x[n][:]). Also:
// padded block sums + degree histogram dhistT (transposed).
__global__ __launch_bounds__(1024, 4) void k_reduce(const unsigned int* __restrict__ partials,
                                                    unsigned char* __restrict__ brel,
                                                    int* __restrict__ deg_out,
                                                    int* __restrict__ blk_sum,
                                                    int* __restrict__ dhistT,
                                                    const float4* __restrict__ x4,
                                                    uint4* __restrict__ xst) {
    __shared__ int sc[256];
    __shared__ int hb[256];
    __shared__ int pre_i[4][256];
    __shared__ int pre_o[4][256];
    __shared__ float rsv[256];
    int t = threadIdx.x;
    int nl = t & 255, ph = t >> 8;
    int pbase = ph * 32;
    int n = blockIdx.x * 256 + nl;
    bool ok = n < N_NODES;
    int w = n >> 1, sh = (n & 1) * 16;
    if (t < 256) hb[t] = 0;
    unsigned v[32];
    int si = 0, so = 0;
    if (ok) {
        #pragma unroll
        for (int j = 0; j < 32; ++j) v[j] = partials[(size_t)(pbase + j) * NW + w];
        #pragma unroll
        for (int j = 0; j < 32; ++j) {
            si += (int)((v[j] >> sh) & 0xFFu);
            so += (int)((v[j] >> (sh + 8)) & 0xFFu);
        }
    }
    pre_i[ph][nl] = si;
    pre_o[ph][nl] = so;
    __syncthreads();
    if (ok) {  // brel[p][n] = # out-edges of n in partitions < p (u8)
        int run = 0;
        #pragma unroll
        for (int q = 0; q < 4; ++q) if (q < ph) run += pre_o[q][nl];
        #pragma unroll
        for (int j = 0; j < 32; ++j) {
            brel[(size_t)(pbase + j) * N_NODES + n] = (unsigned char)run;
            run += (int)((v[j] >> (sh + 8)) & 0xFFu);
        }
    }
    if (ph == 0) {
        int si_t = pre_i[0][nl] + pre_i[1][nl] + pre_i[2][nl] + pre_i[3][nl];
        int so_t = pre_o[0][nl] + pre_o[1][nl] + pre_o[2][nl] + pre_o[3][nl];
        if (ok) {
            deg_out[n] = so_t;
            atomicAdd(&hb[so_t < 255 ? so_t : 255], 1);  // LDS atomics only
        }
        rsv[nl] = rsqrtf((float)(si_t + 1));
        sc[nl] = ok ? ((so_t + 3) & ~3) : 0;  // padded row size (mult of 4)
    }
    __syncthreads();  // rsv, sc visible; hb atomics done
    // fused prescale: 256 nodes x 16 parts = 4096 tasks, 4 per thread, coalesced
    {
        int nbase = blockIdx.x * 256;
        #pragma unroll
        for (int i = 0; i < 4; ++i) {
            int u = t + i * 1024;
            int node_l = u >> 4, part = u & 15;
            int node = nbase + node_l;
            if (node < N_NODES) {
                float rs = rsv[node_l];
                size_t g = (size_t)node * 16 + part;
                float4 a = x4[g * 2], c = x4[g * 2 + 1];
                uint4 o;
                o.x = f2bf(rs * a.x) | ((unsigned)f2bf(rs * a.y) << 16);
                o.y = f2bf(rs * a.z) | ((unsigned)f2bf(rs * a.w) << 16);
                o.z = f2bf(rs * c.x) | ((unsigned)f2bf(rs * c.y) << 16);
                o.w = f2bf(rs * c.z) | ((unsigned)f2bf(rs * c.w) << 16);
                xst[g] = o;
            }
        }
    }
    __syncthreads();
    for (int s = 128; s > 0; s >>= 1) {
        if (t < s) sc[t] += sc[t + s];
        __syncthreads();
    }
    if (t == 0) blk_sum[blockIdx.x] = sc[0];
    if (t < 256) dhistT[t * RNB + blockIdx.x] = hb[t];   // transposed for k_scan_b
}

// block 0: exclusive scan of RNB (padded) block sums + (deg DESC, blk) bins ->
// absolute base offsets dcur[deg][blk]. block 1: W -> bf16 + zero DUMMY row.
__global__ void k_scan_b(const int* __restrict__ blk_sum, int* __restrict__ blk_off,
                         const int* __restrict__ dhistT, int* __restrict__ dcur,
                         const float4* __restrict__ W4, ushort4* __restrict__ Wb4,
                         uint4* __restrict__ xst) {
    int t = threadIdx.x;
    if (blockIdx.x == 1) {
        for (int i = t; i < 4096; i += 256) {  // W: 16384 floats = 4096 float4
            float4 f = W4[i];
            ushort4 h;
            h.x = f2bf(f.x); h.y = f2bf(f.y); h.z = f2bf(f.z); h.w = f2bf(f.w);
            Wb4[i] = h;
        }
        if (t < 16) xst[(size_t)DUMMY * 16 + t] = make_uint4(0, 0, 0, 0);
        return;
    }
    __shared__ int sc[256];
    int v = (t < RNB) ? blk_sum[t] : 0;
    sc[t] = v;
    __syncthreads();
    for (int off = 1; off < 256; off <<= 1) {
        int a = (t >= off) ? sc[t - off] : 0;
        __syncthreads();
        sc[t] += a;
        __syncthreads();
    }
    if (t < RNB) blk_off[t] = sc[t] - v;  // exclusive
    __syncthreads();
    // thread t owns degree d=t; rows of dhistT are contiguous (RNB ints)
    int s = 0;
    #pragma unroll
    for (int i = 0; i < RNB; ++i) s += dhistT[t * RNB + i];
    sc[255 - t] = s;  // descending-degree order: slot u = 255-d
    __syncthreads();
    for (int off = 1; off < 256; off <<= 1) {
        int a = (t >= off) ? sc[t - off] : 0;
        __syncthreads();
        sc[t] += a;
        __syncthreads();
    }
    int run = sc[255 - t] - s;  // exclusive prefix for degree t (descending layout)
    #pragma unroll
    for (int i = 0; i < RNB; ++i) {
        int c = dhistT[t * RNB + i];
        dcur[t * RNB + i] = run;
        run += c;
    }
}

// row_start (PADDED x4) thread-per-node + deterministic degree-sort placement
// + CSR pad-slot fill (DUMMY -> zero row). Writes nd_desc[sorted_pos] =
// {node, row_start, deg, 0} — k_gg reads ONE coalesced int4 instead of
// order[] + 2 dependent random reads (deg_out, row_start).
__global__ void k_scan_c(const int* __restrict__ deg_out, const int* __restrict__ blk_off,
                         int* __restrict__ row_start, const int* __restrict__ dcur,
                         int4* __restrict__ nd_desc, unsigned short* __restrict__ srcs) {
    __shared__ int sc[256];
    __shared__ int lcnt[256];
    int t = threadIdx.x;
    lcnt[t] = 0;
    int n = blockIdx.x * 256 + t;
    int v = (n < N_NODES) ? deg_out[n] : 0;
    int ps = (v + 3) & ~3;
    sc[t] = ps;
    __syncthreads();  // also makes lcnt zeroing visible
    for (int off = 1; off < 256; off <<= 1) {
        int a = (t >= off) ? sc[t - off] : 0;
        __syncthreads();
        sc[t] += a;
        __syncthreads();
    }
    if (n < N_NODES) {
        int base = blk_off[blockIdx.x] + sc[t] - ps;
        row_start[n] = base;
        for (int j = v; j < ps; ++j) srcs[base + j] = DUMMY;
        int d = v < 255 ? v : 255;
        int r = atomicAdd(&lcnt[d], 1);  // LDS atomics only
        nd_desc[dcur[d * RNB + blockIdx.x] + r] = make_int4(n, base, v, 0);
    }
}

// ---- counting-sort placement, 1024 threads, NO global atomics ----
__global__ __launch_bounds__(1024) void k_fill(const int2* __restrict__ el2,
                                               const int* __restrict__ row_start,
                                               const unsigned char* __restrict__ brel,
                                               unsigned short* __restrict__ srcs) {
    __shared__ unsigned int cur[NW];  // 100 KB packed u16 cursors
    int t = threadIdx.x;
    for (int i = t; i < NW / 4; i += 1024) ((uint4*)cur)[i] = make_uint4(0, 0, 0, 0);
    __syncthreads();
    const int2* p = el2 + blockIdx.x * EPB;
    const unsigned char* br = brel + (size_t)blockIdx.x * N_NODES;
    for (int i = t; i < EPB; i += 1024) {
        int2 st = p[i];
        int n = st.y;
        unsigned old = atomicAdd(&cur[n >> 1], 1u << ((n & 1) * 16));
        int rank = (old >> ((n & 1) * 16)) & 0xFFFF;
        srcs[row_start[n] + (int)br[n] + rank] = (unsigned short)st.x;
    }
}

// ---- fused gather + GEMM: per block 128 degree-sorted nodes, 1024 threads.
// R9's best form + 3 latency/cache fixes: (1) nd_desc int4 replaces
// order->deg_out->row_start chain (1 coalesced read vs 1+2 random); (2) node
// id stashed in As spare cols (epilogue reads LDS, not global); (3) out via
// non-temporal stores (write-allocate was dragging ~25MB of out lines through
// L2, evicting the xst gather working set). W staged in LDS; snake + degree
// sort balance per-CU work. min-waves=4 keeps VGPR cap 128 (R3 lesson).
__global__ __launch_bounds__(1024, 4) void k_gg(const unsigned short* __restrict__ Wb,
                                                const float* __restrict__ bias,
                                                const unsigned short* __restrict__ xst,
                                                const unsigned short* __restrict__ srcs,
                                                const int4* __restrict__ nd_desc,
                                                float* __restrict__ out) {
    __shared__ unsigned short Wl[128 * 136];  // 34.8 KB
    __shared__ unsigned short As[128 * 136];  // 34.8 KB (cols 128-135 spare: node id)
    const int tid = threadIdx.x;

    // stage Wb (bf16, 32 KB) -> LDS once per block
    for (int i = tid; i < 2048; i += 1024) {
        int r = i >> 4, c = i & 15;
        *(uint4*)&Wl[r * 136 + c * 8] = ((const uint4*)Wb)[i];
    }

    // snake mapping: rounds of 256, odd rounds reversed
    int b = blockIdx.x;
    int rr = b >> 8, pos = b & 255;
    int rbase = rr << 8;
    int cntr = NBLK - rbase; if (cntr > 256) cntr = 256;
    int tile = (rr & 1) ? (rbase + cntr - 1 - pos) : b;

    // ---- phase 1: gather ----
    const int slot = tid >> 3;            // As row 0..127
    const int d = tid & 7;                // 16-feature slice
    const int gslot = tile * 128 + slot;
    float acc[16];
    #pragma unroll
    for (int i = 0; i < 16; ++i) acc[i] = 0.f;

    if (gslot < N_NODES) {
        const int4 nd = nd_desc[gslot];   // {node, row_start, deg, 0} — coalesced
        const int node = nd.x;
        const int cnt = nd.z;
        const int cntp = (cnt + 3) & ~3;  // padded (pads -> DUMMY zero row)
        const uint4* xb = (const uint4*)xst;
        const int dof = d * 2;
        if (d == 0) *(unsigned*)&As[slot * 136 + 128] = (unsigned)node;  // stash for epilogue
        {   // self term (already rs-scaled)
            const uint4* xr = xb + (size_t)node * 16 + dof;
            acc16(acc, xr[0], xr[1]);
        }
        const unsigned short* p = srcs + nd.y;  // 8B-aligned (rows %4)
        ushort4 s4 = *(const ushort4*)&p[0];
        for (int k = 0; k < cntp; k += 4) {
            ushort4 nx = *(const ushort4*)&p[k + 4];  // prefetch next chunk
            const uint4* r0 = xb + (size_t)s4.x * 16 + dof;
            const uint4* r1 = xb + (size_t)s4.y * 16 + dof;
            const uint4* r2 = xb + (size_t)s4.z * 16 + dof;
            const uint4* r3 = xb + (size_t)s4.w * 16 + dof;
            uint4 a0 = r0[0], b0 = r0[1];
            uint4 a1 = r1[0], b1 = r1[1];
            uint4 a2 = r2[0], b2 = r2[1];
            uint4 a3 = r3[0], b3 = r3[1];
            acc16(acc, a0, b0); acc16(acc, a1, b1);
            acc16(acc, a2, b2); acc16(acc, a3, b3);
            s4 = nx;
        }
        float rd = rsqrtf((float)(cnt + 1));
        #pragma unroll
        for (int i = 0; i < 16; ++i) acc[i] *= rd;
    }
    {   // pack 16 f32 -> 16 bf16 -> LDS (invalid slots write zeros; no early return!)
        unsigned wpk[8];
        #pragma unroll
        for (int i = 0; i < 8; ++i)
            wpk[i] = (unsigned)f2bf(acc[2 * i]) | ((unsigned)f2bf(acc[2 * i + 1]) << 16);
        uint4* dst = (uint4*)&As[slot * 136 + d * 16];
        dst[0] = make_uint4(wpk[0], wpk[1], wpk[2], wpk[3]);
        dst[1] = make_uint4(wpk[4], wpk[5], wpk[6], wpk[7]);
    }
    __syncthreads();

    // ---- phase 2: 128x128 GEMM, 16 waves = 8 row-tiles x 2 col-halves ----
    const int wv = tid >> 6, lane = tid & 63, ml = lane & 15, q = lane >> 4;
    const int rt = wv & 7, half = wv >> 3;
    const int arow = rt * 16 + ml;
    short8 a[4];
    #pragma unroll
    for (int kt = 0; kt < 4; ++kt)
        a[kt] = *(const short8*)&As[arow * 136 + kt * 32 + q * 8];

    f32x4 accm[4];
    #pragma unroll
    for (int jj = 0; jj < 4; ++jj) accm[jj] = (f32x4){0.f, 0.f, 0.f, 0.f};
    #pragma unroll
    for (int jj = 0; jj < 4; ++jj) {
        #pragma unroll
        for (int kt = 0; kt < 4; ++kt) {
            short8 bw = *(const short8*)&Wl[(half * 64 + jj * 16 + ml) * 136 + kt * 32 + q * 8];
            accm[jj] = __builtin_amdgcn_mfma_f32_16x16x32_bf16(a[kt], bw, accm[jj], 0, 0, 0);
        }
    }
    #pragma unroll
    for (int jj = 0; jj < 4; ++jj) {
        float bj = bias[half * 64 + jj * 16 + ml];
        #pragma unroll
        for (int r4 = 0; r4 < 4; ++r4) {
            int s = rt * 16 + q * 4 + r4;
            int gs = tile * 128 + s;
            if (gs < N_NODES) {
                int nd = (int)*(const unsigned*)&As[s * 136 + 128];  // stashed node id
                float v = accm[jj][r4] + bj;
                __builtin_nontemporal_store(v > 0.f ? v : 0.f,
                                            &out[(size_t)nd * D + half * 64 + jj * 16 + ml]);
            }
        }
    }
}

extern "C" void kernel_launch(void* const* d_in, const int* in_sizes, int n_in,
                              void* d_out, int out_size, void* d_ws, size_t ws_size,
                              hipStream_t stream) {
    const int*   el = (const int*)d_in[0];
    const float* x  = (const float*)d_in[1];
    const float* W  = (const float*)d_in[2];
    const float* b  = (const float*)d_in[3];
    float* out = (float*)d_out;

    // workspace layout (~36 MB)
    unsigned int* partials = (unsigned int*)d_ws;                            // HP*NW u32 = 12.8M
    unsigned short* xst    = (unsigned short*)(partials + (size_t)HP * NW);  // (N+1)*128 bf16
    unsigned char* brel    = (unsigned char*)(xst + (size_t)(N_NODES + 1) * D); // HP*N u8 = 6.4M
    unsigned short* srcs   = (unsigned short*)(brel + (size_t)HP * N_NODES); // <=1M u16 (pad x4)
    int* deg_out   = (int*)(srcs + 1000000);                                 // N
    int* row_start = deg_out + N_NODES;                                      // N
    int* blk_sum   = row_start + N_NODES;                                    // 256
    int* blk_off   = blk_sum + 256;                                          // 256
    int* dhistT    = blk_off + 256;                                          // 256*RNB = 50176
    int* dcur      = dhistT + 256 * RNB;                                     // 50176
    int4* nd_desc  = (int4*)(dcur + 256 * RNB);                              // N int4 (16B-aligned)
    unsigned short* Wb = (unsigned short*)(nd_desc + 50176);                 // 128*128 bf16

    k_hist<<<HP, 1024, 0, stream>>>((const int2*)el, partials);
    k_reduce<<<RNB, 1024, 0, stream>>>(partials, brel, deg_out, blk_sum, dhistT,
                                       (const float4*)x, (uint4*)xst);
    k_scan_b<<<2, 256, 0, stream>>>(blk_sum, blk_off, dhistT, dcur,
                                    (const float4*)W, (ushort4*)Wb, (uint4*)xst);
    k_scan_c<<<RNB, 256, 0, stream>>>(deg_out, blk_off, row_start, dcur, nd_desc, srcs);
    k_fill<<<HP, 1024, 0, stream>>>((const int2*)el, row_start, brel, srcs);
    k_gg<<<NBLK, 1024, 0, stream>>>(Wb, b, xst, srcs, nd_desc, out);
}